// Round 1
// 727.320 us; speedup vs baseline: 1.0097x; 1.0097x over previous
//
#include <hip/hip_runtime.h>
#include <limits.h>

#define NUM_Q    4096
#define MAX_STEP 256
#define BATCH    64
#define TWOQ     8192   // 2*NUM_Q
#define ROWS     (BATCH * MAX_STEP)   // 16384
#define ITERS    32     // 32 iters of 64 lanes x float4 = 1 KB per iter, 32 KB per row

// Kernel 1: ONE WAVE per (b,s) row of batch [B,S,2Q]. Scan for the single
// nonzero (one-hot) with early exit via wave ballot; values are exactly 0.0 or
// 1.0 so sum>0 detects a hit. qa[row] = idx in [0,8192) or -1 (padding row).
//
// Changes vs previous version:
//  - no speculative prefetch: on exit the prefetched 1 KB/row was pure waste
//    (~16 MB total). Latency stays hidden: 32 resident waves/CU x 1 KB in
//    flight >> 9.2 KB/CU Little's-law requirement at 6.3 TB/s.
//  - rows with s==0 are skipped entirely: loss only reads qa[b, t+1], t<=254,
//    so qa[b,0] is dead (-1 MB).
//  - lane 0 also gathers p = pred[b, s-1, qid] here (the scattered 4B read the
//    loss kernel used to do over a 256 MB buffer) and stores it to workspace,
//    so kernel 2 only touches 128 KB of L2-hot workspace.
//  - out-zeroing folded in (replaces the hipMemsetAsync dispatch).
__global__ void __launch_bounds__(256) find_onehot_kernel(
        const float* __restrict__ batch,
        const float* __restrict__ pred,
        int* __restrict__ qa,
        float* __restrict__ pw,
        float* __restrict__ out, int out_n) {
    const int gtid = blockIdx.x * blockDim.x + threadIdx.x;
    if (gtid < out_n) out[gtid] = 0.0f;   // replaces memset dispatch

    const int row  = gtid >> 6;        // global wave id = row
    const int lane = gtid & 63;
    if (row >= ROWS) return;
    const int s = row & (MAX_STEP - 1);
    if (s == 0) return;                // qa[b,0] never read by loss kernel

    const float4* rp = (const float4*)(batch + (size_t)row * TWOQ);

    int found = -1;
    for (int it = 0; it < ITERS; ++it) {
        const float4 v = rp[it * 64 + lane];
        const float sum = v.x + v.y + v.z + v.w;         // 0.0 or 1.0
        const unsigned long long m = __ballot(sum > 0.0f); // wave-uniform
        if (m) {
            const int src = __ffsll(m) - 1;
            int idx = 0;
            if (lane == src) {
                const int base = (it * 64 + lane) * 4;
                idx = (v.x != 0.f) ? base
                    : (v.y != 0.f) ? base + 1
                    : (v.z != 0.f) ? base + 2
                                   : base + 3;
            }
            found = __shfl(idx, src);
            break;
        }
    }

    if (lane == 0) {
        qa[row] = found;
        float p = 0.0f;
        if (found >= 0) {
            const int b   = row >> 8;              // row / MAX_STEP
            const int qid = found & (NUM_Q - 1);
            p = pred[((size_t)b * MAX_STEP + (s - 1)) * NUM_Q + qid];
        }
        pw[row] = p;                               // 0.0 for padding rows
    }
}

__device__ __forceinline__ float bce(float p, float a) {
    // matches torch BCELoss: logs clamped at -100. logf(0) = -inf -> clamped.
    float lp  = fmaxf(logf(p), -100.0f);
    float l1p = fmaxf(log1pf(-p), -100.0f);
    return -(a * lp + (1.0f - a) * l1p);
}

// Kernel 2: one block per student b. Reads only qa/pw from workspace (L2-hot).
// Finds trim index i0, sums BCE over s>=i0, adds tail term, divides by
// n = 256 - i0, atomically accumulates into out[0].
__global__ void __launch_bounds__(256) loss_kernel(
        const float* __restrict__ target_q,
        const float* __restrict__ target_label,
        const int* __restrict__ qa,
        const float* __restrict__ pw,
        float* __restrict__ out) {
    const int b    = blockIdx.x;
    const int t    = threadIdx.x;
    const int lane = t & 63;
    const int wid  = t >> 6;
    const int SM1  = MAX_STEP - 1;  // 255

    __shared__ int   smin[4];
    __shared__ float ssum[4];

    // step s = t (covers 0..254), uses qa/pw[b, t+1].
    int   idx = -1;
    float p   = 0.0f;
    if (t < SM1) {
        idx = qa[b * MAX_STEP + t + 1];
        p   = pw[b * MAX_STEP + t + 1];
    }

    // i0 = first s with p > 0 (pred >= 0.01 so any valid gather gives p > 0).
    // argmax of all-false -> 0.
    int cand = (t < SM1 && p > 0.0f) ? t : INT_MAX;
    #pragma unroll
    for (int off = 32; off > 0; off >>= 1)
        cand = min(cand, __shfl_down(cand, off));
    if (lane == 0) smin[wid] = cand;
    __syncthreads();
    int i0 = min(min(smin[0], smin[1]), min(smin[2], smin[3]));
    if (i0 == INT_MAX) i0 = 0;

    // seq_loss: sum BCE over masked steps s >= i0
    float v = 0.0f;
    if (t < SM1 && t >= i0) {
        const float a = (idx >= 0 && idx < NUM_Q) ? 1.0f : 0.0f;
        v = bce(p, a);   // padding rows: bce(0,0) == 0, matches reference
    }
    #pragma unroll
    for (int off = 32; off > 0; off >>= 1)
        v += __shfl_down(v, off);
    if (lane == 0) ssum[wid] = v;
    __syncthreads();

    if (t == 0) {
        const float tail = bce(target_q[b], target_label[b]);
        const float n = (float)(MAX_STEP - i0);  // (S-1) - i0 + 1
        atomicAdd(out, (ssum[0] + ssum[1] + ssum[2] + ssum[3] + tail) / n);
    }
}

extern "C" void kernel_launch(void* const* d_in, const int* in_sizes, int n_in,
                              void* d_out, int out_size, void* d_ws, size_t ws_size,
                              hipStream_t stream) {
    const float* pred         = (const float*)d_in[0];  // [B,S,Q]
    const float* target_q     = (const float*)d_in[1];  // [B,1]
    const float* batch        = (const float*)d_in[2];  // [B,S,2Q]
    const float* target_label = (const float*)d_in[3];  // [B]
    float* out = (float*)d_out;
    int*   qa  = (int*)d_ws;              // ROWS ints   = 64 KB
    float* pw  = (float*)(qa + ROWS);     // ROWS floats = 64 KB

    // one wave per row: ROWS waves = ROWS*64 threads, 256-thread blocks
    find_onehot_kernel<<<(ROWS * 64) / 256, 256, 0, stream>>>(
        batch, pred, qa, pw, out, out_size);
    loss_kernel<<<BATCH, 256, 0, stream>>>(target_q, target_label, qa, pw, out);
}